// Round 3
// baseline (453.072 us; speedup 1.0000x reference)
//
#include <hip/hip_runtime.h>
#include <stdint.h>

#define NHD 8
#define HD  64
#define FEA 512
#define NSQ 512

typedef short bf16x8 __attribute__((ext_vector_type(8)));
typedef float f32x4  __attribute__((ext_vector_type(4)));

__device__ __forceinline__ short f2bf(float f) {
  uint32_t u = __builtin_bit_cast(uint32_t, f);
  u = (u + 0x7FFFu + ((u >> 16) & 1u)) >> 16;
  return (short)(uint16_t)u;
}
__device__ __forceinline__ float bf2f(short s) {
  uint32_t u = ((uint32_t)(uint16_t)s) << 16;
  return __builtin_bit_cast(float, u);
}

__device__ __forceinline__ void gld16(const void* g, void* l) {
  __builtin_amdgcn_global_load_lds((const __attribute__((address_space(1))) void*)g,
                                   (__attribute__((address_space(3))) void*)l, 16, 0, 0);
}

// ---- weight transpose + split/convert: W[in][out] -> Wt[out][in] ----
// z=0: Wq*8 -> hi/lo  z=1: Wk -> hi/lo  z=2: Wv -> bf16  z=3: Wo -> bf16
__global__ void wconv(const float* __restrict__ Wq, const float* __restrict__ Wk,
                      const float* __restrict__ Wv, const float* __restrict__ Wo,
                      short* __restrict__ Wqk_h, short* __restrict__ Wqk_l,
                      short* __restrict__ WvT, short* __restrict__ WoT) {
  __shared__ float tile[32][33];
  int z = blockIdx.z;
  const float* src = (z == 0) ? Wq : (z == 1) ? Wk : (z == 2) ? Wv : Wo;
  float scale = (z == 0) ? 8.0f : 1.0f;   // fold sqrt(d)=8 into Wq
  int rb = blockIdx.y * 32, cb = blockIdx.x * 32;
  int c = threadIdx.x & 31, r0 = threadIdx.x >> 5;
#pragma unroll
  for (int k = 0; k < 4; k++) {
    int r = r0 + k * 8;
    tile[r][c] = src[(size_t)(rb + r) * FEA + cb + c];
  }
  __syncthreads();
#pragma unroll
  for (int k = 0; k < 4; k++) {
    int o = r0 + k * 8;
    float val = tile[c][o] * scale;
    if (z < 2) {
      short hi = f2bf(val);
      short lo = f2bf(val - bf2f(hi));
      size_t idx = (size_t)(z * FEA + cb + o) * FEA + rb + c;
      Wqk_h[idx] = hi; Wqk_l[idx] = lo;
    } else {
      short* dst = (z == 2) ? WvT : WoT;
      dst[(size_t)(cb + o) * FEA + rb + c] = f2bf(val);
    }
  }
}

// ---- ndata fp32 -> bf16 hi/lo ----
__global__ void xconv(const float* __restrict__ x, short* __restrict__ xh, short* __restrict__ xl) {
  int i = (blockIdx.x * 256 + threadIdx.x) * 8;
  float4 a = *(const float4*)(x + i);
  float4 b = *(const float4*)(x + i + 4);
  float v[8] = {a.x, a.y, a.z, a.w, b.x, b.y, b.z, b.w};
  bf16x8 h, l;
#pragma unroll
  for (int j = 0; j < 8; j++) {
    short hi = f2bf(v[j]);
    h[j] = hi;
    l[j] = f2bf(v[j] - bf2f(hi));
  }
  *(bf16x8*)(xh + i) = h;
  *(bf16x8*)(xl + i) = l;
}

// ---- high-precision Q/K projection: C = X @ Wqk^T with split-bf16 operands ----
// acc = Ah*Bh + Al*Bh + Ah*Bl  (rel err ~2^-17). Outputs hi/lo bf16 pairs.
__global__ void __launch_bounds__(256, 2) gemm_qk(
    const short* __restrict__ Agh, const short* __restrict__ Agl,
    const short* __restrict__ Bgh, const short* __restrict__ Bgl,
    const float* __restrict__ bq, const float* __restrict__ bk,
    short* __restrict__ Qh, short* __restrict__ Ql,
    short* __restrict__ Kh, short* __restrict__ Kl)
{
  __shared__ short Ah[128 * 32], Al[128 * 32], Bh[128 * 32], Bl[128 * 32];
  const int K = FEA;
  int tid = threadIdx.x;
  int l = tid & 63, w = tid >> 6;
  int wr = w >> 1, wc = w & 1;
  int m0 = blockIdx.x * 128, n0 = blockIdx.y * 128;
  int c = l & 15, g = l >> 4;

  f32x4 acc[4][4];
#pragma unroll
  for (int i = 0; i < 4; i++)
#pragma unroll
    for (int j = 0; j < 4; j++) acc[i][j] = f32x4{0.f, 0.f, 0.f, 0.f};

  int srow = w * 32 + (l >> 2);
  int scol = (l & 3) * 8;
  const short* gah = Agh + (size_t)(m0 + srow) * K + scol;
  const short* gal = Agl + (size_t)(m0 + srow) * K + scol;
  const short* gbh = Bgh + (size_t)(n0 + srow) * K + scol;
  const short* gbl = Bgl + (size_t)(n0 + srow) * K + scol;
  short* lah0 = Ah + w * 1024; short* lah1 = lah0 + 512;
  short* lal0 = Al + w * 1024; short* lal1 = lal0 + 512;
  short* lbh0 = Bh + w * 1024; short* lbh1 = lbh0 + 512;
  short* lbl0 = Bl + w * 1024; short* lbl1 = lbl0 + 512;

  for (int kt = 0; kt < 16; ++kt) {
    const int k0 = kt * 32;
    __syncthreads();
    gld16(gah + k0, lah0); gld16(gah + (size_t)16 * K + k0, lah1);
    gld16(gal + k0, lal0); gld16(gal + (size_t)16 * K + k0, lal1);
    gld16(gbh + k0, lbh0); gld16(gbh + (size_t)16 * K + k0, lbh1);
    gld16(gbl + k0, lbl0); gld16(gbl + (size_t)16 * K + k0, lbl1);
    asm volatile("s_waitcnt vmcnt(0)" ::: "memory");
    __syncthreads();
    bf16x8 afh[4], afl[4], bfh[4], bfl[4];
#pragma unroll
    for (int mi = 0; mi < 4; mi++) {
      afh[mi] = *(const bf16x8*)(Ah + (wr * 64 + mi * 16 + c) * 32 + g * 8);
      afl[mi] = *(const bf16x8*)(Al + (wr * 64 + mi * 16 + c) * 32 + g * 8);
    }
#pragma unroll
    for (int ni = 0; ni < 4; ni++) {
      bfh[ni] = *(const bf16x8*)(Bh + (wc * 64 + ni * 16 + c) * 32 + g * 8);
      bfl[ni] = *(const bf16x8*)(Bl + (wc * 64 + ni * 16 + c) * 32 + g * 8);
    }
#pragma unroll
    for (int mi = 0; mi < 4; mi++)
#pragma unroll
      for (int ni = 0; ni < 4; ni++) {
        acc[mi][ni] = __builtin_amdgcn_mfma_f32_16x16x32_bf16(afh[mi], bfh[ni], acc[mi][ni], 0, 0, 0);
        acc[mi][ni] = __builtin_amdgcn_mfma_f32_16x16x32_bf16(afl[mi], bfh[ni], acc[mi][ni], 0, 0, 0);
        acc[mi][ni] = __builtin_amdgcn_mfma_f32_16x16x32_bf16(afh[mi], bfl[ni], acc[mi][ni], 0, 0, 0);
      }
  }

#pragma unroll
  for (int ni = 0; ni < 4; ni++) {
    int gn = n0 + wc * 64 + ni * 16 + c;
    int sec = gn >> 9, f = gn & 511;
    float bb = sec ? bk[f] : bq[f] * 8.0f;
    short* dh = sec ? Kh : Qh;
    short* dl = sec ? Kl : Ql;
#pragma unroll
    for (int mi = 0; mi < 4; mi++) {
      int gm0 = m0 + wr * 64 + mi * 16 + g * 4;
#pragma unroll
      for (int r = 0; r < 4; r++) {
        float val = acc[mi][ni][r] + bb;
        short hi = f2bf(val);
        size_t idx = (size_t)(gm0 + r) * FEA + f;
        dh[idx] = hi;
        dl[idx] = f2bf(val - bf2f(hi));
      }
    }
  }
}

// ---- 128x128x(K=512) bf16 MFMA GEMM. MODE 0: V (writes V transposed)
//      MODE 1: out-proj (writes fp32 d_out) ----
template<int MODE>
__global__ void __launch_bounds__(256, 3) gemm_k(
    const short* __restrict__ A, const short* __restrict__ Bt,
    const float* __restrict__ bias0,
    short* __restrict__ Vt, float* __restrict__ Fo)
{
  __shared__ short As[128 * 32];
  __shared__ short Bs[128 * 32];
  const int K = FEA;
  int tid = threadIdx.x;
  int l = tid & 63, w = tid >> 6;
  int wr = w >> 1, wc = w & 1;
  int m0 = blockIdx.x * 128, n0 = blockIdx.y * 128;
  int c = l & 15, g = l >> 4;

  f32x4 acc[4][4];
#pragma unroll
  for (int i = 0; i < 4; i++)
#pragma unroll
    for (int j = 0; j < 4; j++) acc[i][j] = f32x4{0.f, 0.f, 0.f, 0.f};

  int srow = w * 32 + (l >> 2);
  int scol = (l & 3) * 8;
  const short* ga = A + (size_t)(m0 + srow) * K + scol;
  const short* gb = Bt + (size_t)(n0 + srow) * K + scol;
  short* la0 = As + w * 1024;
  short* la1 = As + w * 1024 + 512;
  short* lb0 = Bs + w * 1024;
  short* lb1 = Bs + w * 1024 + 512;

  for (int kt = 0; kt < 16; ++kt) {
    const int k0 = kt * 32;
    __syncthreads();
    gld16(ga + k0, la0);
    gld16(ga + (size_t)16 * K + k0, la1);
    gld16(gb + k0, lb0);
    gld16(gb + (size_t)16 * K + k0, lb1);
    asm volatile("s_waitcnt vmcnt(0)" ::: "memory");
    __syncthreads();
    bf16x8 af[4], bf[4];
#pragma unroll
    for (int mi = 0; mi < 4; mi++)
      af[mi] = *(const bf16x8*)(As + (wr * 64 + mi * 16 + c) * 32 + g * 8);
#pragma unroll
    for (int ni = 0; ni < 4; ni++)
      bf[ni] = *(const bf16x8*)(Bs + (wc * 64 + ni * 16 + c) * 32 + g * 8);
#pragma unroll
    for (int mi = 0; mi < 4; mi++)
#pragma unroll
      for (int ni = 0; ni < 4; ni++)
        acc[mi][ni] = __builtin_amdgcn_mfma_f32_16x16x32_bf16(af[mi], bf[ni], acc[mi][ni], 0, 0, 0);
  }

#pragma unroll
  for (int ni = 0; ni < 4; ni++) {
    int gn = n0 + wc * 64 + ni * 16 + c;
    float bb = bias0[gn];
#pragma unroll
    for (int mi = 0; mi < 4; mi++) {
      int gm0 = m0 + wr * 64 + mi * 16 + g * 4;
      if (MODE == 0) {
        int b = gm0 >> 9, i = gm0 & 511;
        uint16_t pk[4];
#pragma unroll
        for (int r = 0; r < 4; r++) pk[r] = (uint16_t)f2bf(acc[mi][ni][r] + bb);
        uint2 val;
        val.x = (uint32_t)pk[0] | ((uint32_t)pk[1] << 16);
        val.y = (uint32_t)pk[2] | ((uint32_t)pk[3] << 16);
        *(uint2*)(Vt + ((size_t)b * FEA + gn) * NSQ + i) = val;
      } else {
#pragma unroll
        for (int r = 0; r < 4; r++)
          Fo[(size_t)(gm0 + r) * FEA + gn] = acc[mi][ni][r] + bb;
      }
    }
  }
}

// ---- fused biased+masked+multiplied attention, flash-style over j ----
// block = (b, 16-row i tile), 8 waves = 8 heads, j-tile = 32
__global__ void __launch_bounds__(512, 4) attn_k(
    const short* __restrict__ Qh, const short* __restrict__ Ql,
    const short* __restrict__ Kh, const short* __restrict__ Kl,
    const short* __restrict__ Vt,
    const float* __restrict__ bias, const int* __restrict__ mask, const float* __restrict__ mul,
    short* __restrict__ Op)
{
  __shared__ float biasS[NHD][16][36];
  __shared__ float mulS[NHD][16][36];
  __shared__ int   maskS[16][36];
  __shared__ short pS[NHD][16][40];   // 80B row stride: 16B-aligned b128 reads

  int bid = blockIdx.x;
  int b = bid >> 5, i0 = (bid & 31) << 4;
  int tid = threadIdx.x, l = tid & 63, h = tid >> 6;
  int c = l & 15, g = l >> 4;

  bf16x8 qh0, qh1, ql0, ql1;
  {
    size_t off = ((size_t)(b * NSQ + i0 + c)) * FEA + h * HD + g * 8;
    qh0 = *(const bf16x8*)(Qh + off);
    qh1 = *(const bf16x8*)(Qh + off + 32);
    ql0 = *(const bf16x8*)(Ql + off);
    ql1 = *(const bf16x8*)(Ql + off + 32);
  }
  float mrun[4], lrun[4];
  f32x4 acc[4];
#pragma unroll
  for (int r = 0; r < 4; r++) { mrun[r] = -3e38f; lrun[r] = 0.f; }
#pragma unroll
  for (int fd = 0; fd < 4; fd++) acc[fd] = f32x4{0.f, 0.f, 0.f, 0.f};

  int sii = tid >> 5, sjj = tid & 31;
  const size_t rowb = (size_t)(b * NSQ + i0 + sii) * NSQ;
  const float* bROW = bias + rowb * NHD;
  const float* mROW = mul + rowb * NHD;
  const int* kROW = mask + rowb;

  for (int jt = 0; jt < 16; ++jt) {
    const int j0 = jt * 32;
    __syncthreads();
    {
      const float* bp = bROW + (size_t)(j0 + sjj) * NHD;
      float4 x0 = *(const float4*)bp;
      float4 x1 = *(const float4*)(bp + 4);
      biasS[0][sii][sjj] = x0.x; biasS[1][sii][sjj] = x0.y;
      biasS[2][sii][sjj] = x0.z; biasS[3][sii][sjj] = x0.w;
      biasS[4][sii][sjj] = x1.x; biasS[5][sii][sjj] = x1.y;
      biasS[6][sii][sjj] = x1.z; biasS[7][sii][sjj] = x1.w;
      const float* mp = mROW + (size_t)(j0 + sjj) * NHD;
      float4 y0 = *(const float4*)mp;
      float4 y1 = *(const float4*)(mp + 4);
      mulS[0][sii][sjj] = y0.x; mulS[1][sii][sjj] = y0.y;
      mulS[2][sii][sjj] = y0.z; mulS[3][sii][sjj] = y0.w;
      mulS[4][sii][sjj] = y1.x; mulS[5][sii][sjj] = y1.y;
      mulS[6][sii][sjj] = y1.z; mulS[7][sii][sjj] = y1.w;
      maskS[sii][sjj] = kROW[j0 + sjj];
    }
    __syncthreads();

    // S = q @ k^T for this head, 16i x 32j, split-bf16: qh*kh + ql*kh + qh*kl
    f32x4 S0 = f32x4{0.f, 0.f, 0.f, 0.f};
    f32x4 S1 = f32x4{0.f, 0.f, 0.f, 0.f};
    {
      size_t koff = ((size_t)(b * NSQ + j0 + c)) * FEA + h * HD + g * 8;
      bf16x8 kh0 = *(const bf16x8*)(Kh + koff);
      bf16x8 kh1 = *(const bf16x8*)(Kh + koff + 32);
      bf16x8 kl0 = *(const bf16x8*)(Kl + koff);
      bf16x8 kl1 = *(const bf16x8*)(Kl + koff + 32);
      S0 = __builtin_amdgcn_mfma_f32_16x16x32_bf16(qh0, kh0, S0, 0, 0, 0);
      S0 = __builtin_amdgcn_mfma_f32_16x16x32_bf16(qh1, kh1, S0, 0, 0, 0);
      S0 = __builtin_amdgcn_mfma_f32_16x16x32_bf16(ql0, kh0, S0, 0, 0, 0);
      S0 = __builtin_amdgcn_mfma_f32_16x16x32_bf16(ql1, kh1, S0, 0, 0, 0);
      S0 = __builtin_amdgcn_mfma_f32_16x16x32_bf16(qh0, kl0, S0, 0, 0, 0);
      S0 = __builtin_amdgcn_mfma_f32_16x16x32_bf16(qh1, kl1, S0, 0, 0, 0);
      size_t koff2 = koff + (size_t)16 * FEA;
      bf16x8 m0f = *(const bf16x8*)(Kh + koff2);
      bf16x8 m1f = *(const bf16x8*)(Kh + koff2 + 32);
      bf16x8 n0f = *(const bf16x8*)(Kl + koff2);
      bf16x8 n1f = *(const bf16x8*)(Kl + koff2 + 32);
      S1 = __builtin_amdgcn_mfma_f32_16x16x32_bf16(qh0, m0f, S1, 0, 0, 0);
      S1 = __builtin_amdgcn_mfma_f32_16x16x32_bf16(qh1, m1f, S1, 0, 0, 0);
      S1 = __builtin_amdgcn_mfma_f32_16x16x32_bf16(ql0, m0f, S1, 0, 0, 0);
      S1 = __builtin_amdgcn_mfma_f32_16x16x32_bf16(ql1, m1f, S1, 0, 0, 0);
      S1 = __builtin_amdgcn_mfma_f32_16x16x32_bf16(qh0, n0f, S1, 0, 0, 0);
      S1 = __builtin_amdgcn_mfma_f32_16x16x32_bf16(qh1, n1f, S1, 0, 0, 0);
    }

    float p0[4], p1[4], rm[4];
#pragma unroll
    for (int r = 0; r < 4; r++) {
      int il = g * 4 + r;
      float s0 = S0[r] + biasS[h][il][c];
      float s1 = S1[r] + biasS[h][il][16 + c];
      if (maskS[il][c]) s0 = -1e30f;           // mask!=0 -> blocked
      if (maskS[il][16 + c]) s1 = -1e30f;
      p0[r] = s0; p1[r] = s1;
      rm[r] = fmaxf(s0, s1);
    }
#pragma unroll
    for (int off = 8; off >= 1; off >>= 1)
#pragma unroll
      for (int r = 0; r < 4; r++)
        rm[r] = fmaxf(rm[r], __shfl_xor(rm[r], off));

    float scal[4], rs[4];
#pragma unroll
    for (int r = 0; r < 4; r++) {
      float nm = fmaxf(mrun[r], rm[r]);
      scal[r] = __expf(mrun[r] - nm);
      p0[r] = __expf(p0[r] - nm);
      p1[r] = __expf(p1[r] - nm);
      mrun[r] = nm;
      rs[r] = p0[r] + p1[r];
    }
#pragma unroll
    for (int off = 8; off >= 1; off >>= 1)
#pragma unroll
      for (int r = 0; r < 4; r++)
        rs[r] += __shfl_xor(rs[r], off);
#pragma unroll
    for (int r = 0; r < 4; r++) lrun[r] = lrun[r] * scal[r] + rs[r];
#pragma unroll
    for (int fd = 0; fd < 4; fd++)
#pragma unroll
      for (int r = 0; r < 4; r++) acc[fd][r] *= scal[r];

    // P' = p * mul -> per-wave LDS, then A-fragment
#pragma unroll
    for (int r = 0; r < 4; r++) {
      int il = g * 4 + r;
      pS[h][il][c]      = f2bf(p0[r] * mulS[h][il][c]);
      pS[h][il][16 + c] = f2bf(p1[r] * mulS[h][il][16 + c]);
    }
    bf16x8 pa = *(const bf16x8*)&pS[h][c][g * 8];
#pragma unroll
    for (int fd = 0; fd < 4; fd++) {
      const short* vp = Vt + ((size_t)(b * FEA + h * HD + fd * 16 + c)) * NSQ + j0 + g * 8;
      bf16x8 bvf = *(const bf16x8*)vp;
      acc[fd] = __builtin_amdgcn_mfma_f32_16x16x32_bf16(pa, bvf, acc[fd], 0, 0, 0);
    }
  }

  float inv[4];
#pragma unroll
  for (int r = 0; r < 4; r++) inv[r] = 1.0f / lrun[r];
#pragma unroll
  for (int fd = 0; fd < 4; fd++)
#pragma unroll
    for (int r = 0; r < 4; r++) {
      int i = i0 + g * 4 + r;
      Op[((size_t)(b * NSQ + i)) * FEA + h * HD + fd * 16 + c] = f2bf(acc[fd][r] * inv[r]);
    }
}

extern "C" void kernel_launch(void* const* d_in, const int* in_sizes, int n_in,
                              void* d_out, int out_size, void* d_ws, size_t ws_size,
                              hipStream_t stream) {
  (void)in_sizes; (void)n_in; (void)out_size; (void)ws_size;
  const float* ndata = (const float*)d_in[0];
  const float* abias = (const float*)d_in[1];
  const int*   amask = (const int*)d_in[2];
  const float* amul  = (const float*)d_in[3];
  const float* Wq = (const float*)d_in[4];
  const float* bq = (const float*)d_in[5];
  const float* Wk = (const float*)d_in[6];
  const float* bk = (const float*)d_in[7];
  const float* Wv = (const float*)d_in[8];
  const float* bv = (const float*)d_in[9];
  const float* Wo = (const float*)d_in[10];
  const float* bo = (const float*)d_in[11];
  float* out = (float*)d_out;

  char* ws = (char*)d_ws;
  short* Wqk_h = (short*)(ws);                    // [1024][512] bf16
  short* Wqk_l = (short*)(ws + 1048576);          // [1024][512] bf16
  short* WvT   = (short*)(ws + 2097152);          // [512][512] bf16
  short* WoT   = (short*)(ws + 2621440);          // [512][512] bf16
  short* Xh    = (short*)(ws + 3145728);          // [8192][512] bf16
  short* Xl    = (short*)(ws + 11534336);         // [8192][512] bf16
  short* Qh    = (short*)(ws + 19922944);         // [8192][512] bf16
  short* Ql    = (short*)(ws + 28311552);         // [8192][512] bf16
  short* Kh    = (short*)(ws + 36700160);         // [8192][512] bf16
  short* Kl    = (short*)(ws + 45088768);         // [8192][512] bf16
  short* Vt    = (short*)(ws + 53477376);         // [16][512f][512j] bf16 (transposed)
  short* Op    = Xh;                              // alias: Xh dead after gemm_v

  wconv<<<dim3(16, 16, 4), 256, 0, stream>>>(Wq, Wk, Wv, Wo, Wqk_h, Wqk_l, WvT, WoT);
  xconv<<<2048, 256, 0, stream>>>(ndata, Xh, Xl);
  gemm_qk<<<dim3(64, 8), 256, 0, stream>>>(Xh, Xl, Wqk_h, Wqk_l, bq, bk, Qh, Ql, Kh, Kl);
  gemm_k<0><<<dim3(64, 4), 256, 0, stream>>>(Xh, WvT, bv, Vt, nullptr);
  attn_k<<<512, 512, 0, stream>>>(Qh, Ql, Kh, Kl, Vt, abias, amask, amul, Op);
  gemm_k<1><<<dim3(64, 4), 256, 0, stream>>>(Op, WoT, bo, nullptr, out);
}